// Round 1
// baseline (1498.141 us; speedup 1.0000x reference)
//
#include <hip/hip_runtime.h>
#include <cmath>

#define SEQ 2048
#define BATCH 2
#define HID 1024
#define NH 16
#define NKV 4
#define DH 64
#define KVDIM 256   // NKV*DH

// ---------------- GEMM: C[M,N] = A[M,K] @ W[K,N] + bias[N] ----------------
// 64x64 tile, BK=16, 256 threads, 4x4 microtile. LDS padded to 68 (2-way max).
__global__ __launch_bounds__(256) void gemm_bias_kernel(
    const float* __restrict__ A, const float* __restrict__ W,
    const float* __restrict__ bias, float* __restrict__ C,
    int M, int N, int K) {
  __shared__ float As[16][68];
  __shared__ float Bs[16][68];
  const int tid = threadIdx.x;
  const int bm = blockIdx.y * 64;
  const int bn = blockIdx.x * 64;
  const int mb = (tid >> 4) << 2;   // row of 4
  const int nb = (tid & 15) << 2;   // col of 4
  float acc[4][4] = {};
  for (int k0 = 0; k0 < K; k0 += 16) {
#pragma unroll
    for (int i = 0; i < 4; ++i) {
      int idx = tid + i * 256;          // 0..1023
      int kk = idx & 15, m = idx >> 4;  // coalesced along k
      As[kk][m] = A[(size_t)(bm + m) * K + k0 + kk];
    }
#pragma unroll
    for (int i = 0; i < 4; ++i) {
      int idx = tid + i * 256;
      int n = idx & 63, kk = idx >> 6;  // coalesced along n
      Bs[kk][n] = W[(size_t)(k0 + kk) * N + bn + n];
    }
    __syncthreads();
#pragma unroll
    for (int kk = 0; kk < 16; ++kk) {
      float4 a4 = *(const float4*)&As[kk][mb];
      float4 b4 = *(const float4*)&Bs[kk][nb];
      float av[4] = {a4.x, a4.y, a4.z, a4.w};
      float bv[4] = {b4.x, b4.y, b4.z, b4.w};
#pragma unroll
      for (int i = 0; i < 4; ++i)
#pragma unroll
        for (int j = 0; j < 4; ++j)
          acc[i][j] = fmaf(av[i], bv[j], acc[i][j]);
    }
    __syncthreads();
  }
#pragma unroll
  for (int i = 0; i < 4; ++i) {
    float4 r;
    r.x = acc[i][0] + bias[bn + nb + 0];
    r.y = acc[i][1] + bias[bn + nb + 1];
    r.z = acc[i][2] + bias[bn + nb + 2];
    r.w = acc[i][3] + bias[bn + nb + 3];
    *(float4*)&C[(size_t)(bm + mb + i) * N + bn + nb] = r;
  }
}

// --------- RoPE(half=512) + per-head rmsnorm + transpose for Q -------------
// grid (SEQ, BATCH), block 1024. Wave w = head w (64 lanes = 64 dims).
__global__ __launch_bounds__(1024) void rope_norm_q_kernel(
    const float* __restrict__ q, float* __restrict__ qn) {
  const int s = blockIdx.x, b = blockIdx.y;
  const int t = threadIdx.x;            // 0..1023
  const float* row = q + ((size_t)b * SEQ + s) * HID;
  const int j = t & 511;
  double invf = pow(10000.0, -(double)j / 512.0);
  double ang = (double)s * invf;
  float c = (float)cos(ang), sn = (float)sin(ang);
  float x1 = row[j], x2 = row[j + 512];
  float val = (t < 512) ? (x1 * c - x2 * sn) : (x2 * c + x1 * sn);
  float ss = val * val;
#pragma unroll
  for (int off = 1; off < 64; off <<= 1) ss += __shfl_xor(ss, off);
  float rn = rsqrtf(ss * (1.0f / 64.0f) + 1.1920929e-07f);
  int h = t >> 6, d = t & 63;
  qn[(((size_t)b * NH + h) * SEQ + s) * DH + d] = val * rn;
}

// --------- RoPE(half=128) + rmsnorm + transpose for K; transpose V ---------
// grid (SEQ, BATCH), block 256. Wave w = kv head w.
__global__ __launch_bounds__(256) void rope_norm_kv_kernel(
    const float* __restrict__ k, const float* __restrict__ v,
    float* __restrict__ kn, float* __restrict__ vt) {
  const int s = blockIdx.x, b = blockIdx.y;
  const int t = threadIdx.x;            // 0..255
  const float* krow = k + ((size_t)b * SEQ + s) * KVDIM;
  const float* vrow = v + ((size_t)b * SEQ + s) * KVDIM;
  const int j = t & 127;
  double invf = pow(10000.0, -(double)j / 128.0);
  double ang = (double)s * invf;
  float c = (float)cos(ang), sn = (float)sin(ang);
  float x1 = krow[j], x2 = krow[j + 128];
  float val = (t < 128) ? (x1 * c - x2 * sn) : (x2 * c + x1 * sn);
  float ss = val * val;
#pragma unroll
  for (int off = 1; off < 64; off <<= 1) ss += __shfl_xor(ss, off);
  float rn = rsqrtf(ss * (1.0f / 64.0f) + 1.1920929e-07f);
  int h = t >> 6, d = t & 63;
  size_t o = (((size_t)b * NKV + h) * SEQ + s) * DH + d;
  kn[o] = val * rn;
  vt[o] = vrow[t];
}

// ------------------------------ Attention ----------------------------------
// grid (SEQ/128, NH, BATCH), block 256 = 128 q-rows, 2 lanes per row (32 dims
// each). Fixed softmax max = 8 (valid: rmsnorm => |q.k|/8 <= 8, mask == 0).
__global__ __launch_bounds__(256) void attn_kernel(
    const float* __restrict__ qn, const float* __restrict__ kn,
    const float* __restrict__ vt, const float* __restrict__ mask,
    float* __restrict__ out) {
  __shared__ float Ks[64][64];
  __shared__ float Vs[64][64];
  const int b = blockIdx.z, h = blockIdx.y;
  const int kvh = h >> 2;
  const int tid = threadIdx.x;
  const int half = tid & 1;
  const int r = blockIdx.x * 128 + (tid >> 1);
  const float* qrow = qn + (((size_t)b * NH + h) * SEQ + r) * DH + half * 32;
  float4 q[8];
#pragma unroll
  for (int t = 0; t < 8; ++t) q[t] = ((const float4*)qrow)[t];
  float4 o[8] = {};
  float l = 0.0f;
  const float* Kbase = kn + ((size_t)b * NKV + kvh) * SEQ * DH;
  const float* Vbase = vt + ((size_t)b * NKV + kvh) * SEQ * DH;
  const float* mrow = mask + ((size_t)b * SEQ + r) * SEQ;

  for (int j0 = 0; j0 < SEQ; j0 += 64) {
    __syncthreads();
#pragma unroll
    for (int w = 0; w < 4; ++w) {
      int idx = tid + w * 256;  // 1024 float4 = 64x64 floats
      ((float4*)Ks)[idx] = ((const float4*)(Kbase + (size_t)j0 * DH))[idx];
      ((float4*)Vs)[idx] = ((const float4*)(Vbase + (size_t)j0 * DH))[idx];
    }
    __syncthreads();
#pragma unroll 1
    for (int j4 = 0; j4 < 16; ++j4) {
      float4 mk = *(const float4*)(mrow + j0 + j4 * 4);
      float mks[4] = {mk.x, mk.y, mk.z, mk.w};
#pragma unroll
      for (int jj = 0; jj < 4; ++jj) {
        int j = j4 * 4 + jj;
        const float4* kr = (const float4*)&Ks[j][half * 32];
        float s0 = 0, s1 = 0, s2 = 0, s3 = 0;
#pragma unroll
        for (int t = 0; t < 8; ++t) {
          float4 k4 = kr[t];
          s0 = fmaf(q[t].x, k4.x, s0);
          s1 = fmaf(q[t].y, k4.y, s1);
          s2 = fmaf(q[t].z, k4.z, s2);
          s3 = fmaf(q[t].w, k4.w, s3);
        }
        float sp = (s0 + s1) + (s2 + s3);
        sp += __shfl_xor(sp, 1);            // combine the two half-dots
        float sc = sp * 0.125f + mks[jj];
        float p = __expf(sc - 8.0f);
        l += p;
        const float4* vr = (const float4*)&Vs[j][half * 32];
#pragma unroll
        for (int t = 0; t < 8; ++t) {
          float4 vv = vr[t];
          o[t].x = fmaf(p, vv.x, o[t].x);
          o[t].y = fmaf(p, vv.y, o[t].y);
          o[t].z = fmaf(p, vv.z, o[t].z);
          o[t].w = fmaf(p, vv.w, o[t].w);
        }
      }
    }
  }
  float inv = 1.0f / l;
  float* orow = out + ((size_t)b * SEQ + r) * HID + h * DH + half * 32;
#pragma unroll
  for (int t = 0; t < 8; ++t) {
    float4 ov = o[t];
    ov.x *= inv; ov.y *= inv; ov.z *= inv; ov.w *= inv;
    ((float4*)orow)[t] = ov;
  }
}

extern "C" void kernel_launch(void* const* d_in, const int* in_sizes, int n_in,
                              void* d_out, int out_size, void* d_ws, size_t ws_size,
                              hipStream_t stream) {
  const float* hs   = (const float*)d_in[0];
  const float* mask = (const float*)d_in[1];
  const float* Wq   = (const float*)d_in[2];
  const float* bq   = (const float*)d_in[3];
  const float* Wk   = (const float*)d_in[4];
  const float* bk   = (const float*)d_in[5];
  const float* Wv   = (const float*)d_in[6];
  const float* bv   = (const float*)d_in[7];
  const float* Wo   = (const float*)d_in[8];
  const float* bo   = (const float*)d_in[9];
  float* out = (float*)d_out;
  float* ws  = (float*)d_ws;

  // Workspace layout (floats): peak 12M floats = 48 MB
  float* q_proj  = ws;              // 4M
  float* k_proj  = ws + 4194304;    // 1M
  float* v_proj  = ws + 5242880;    // 1M
  float* qn      = ws + 6291456;    // 4M  (B,NH,S,DH)
  float* kn      = ws + 10485760;   // 1M  (B,NKV,S,DH)
  float* vt      = ws + 11534336;   // 1M  (B,NKV,S,DH)
  float* attn_o  = ws;              // reuse q_proj region (B,S,HID)

  const int M = BATCH * SEQ;  // 4096
  dim3 blk(256);
  gemm_bias_kernel<<<dim3(HID / 64, M / 64), blk, 0, stream>>>(hs, Wq, bq, q_proj, M, HID, HID);
  gemm_bias_kernel<<<dim3(KVDIM / 64, M / 64), blk, 0, stream>>>(hs, Wk, bk, k_proj, M, KVDIM, HID);
  gemm_bias_kernel<<<dim3(KVDIM / 64, M / 64), blk, 0, stream>>>(hs, Wv, bv, v_proj, M, KVDIM, HID);
  rope_norm_q_kernel<<<dim3(SEQ, BATCH), dim3(1024), 0, stream>>>(q_proj, qn);
  rope_norm_kv_kernel<<<dim3(SEQ, BATCH), dim3(256), 0, stream>>>(k_proj, v_proj, kn, vt);
  attn_kernel<<<dim3(SEQ / 128, NH, BATCH), dim3(256), 0, stream>>>(qn, kn, vt, mask, attn_o);
  gemm_bias_kernel<<<dim3(HID / 64, M / 64), blk, 0, stream>>>(attn_o, Wo, bo, out, M, HID, HID);
}

// Round 2
// 631.451 us; speedup vs baseline: 2.3725x; 2.3725x over previous
//
#include <hip/hip_runtime.h>
#include <cmath>

#define SEQ 2048
#define BATCH 2
#define HID 1024
#define NH 16
#define NKV 4
#define DH 64
#define KVDIM 256   // NKV*DH

typedef __attribute__((ext_vector_type(8))) short bf16x8;
typedef __attribute__((ext_vector_type(4))) float f32x4;

static __device__ __forceinline__ unsigned short f2bf(float x) {
  union { float f; unsigned u; } v; v.f = x;
  unsigned r = v.u + 0x7fffu + ((v.u >> 16) & 1u);  // RNE
  return (unsigned short)(r >> 16);
}
static __device__ __forceinline__ float bf2f(unsigned short h) {
  union { unsigned u; float f; } v; v.u = ((unsigned)h) << 16;
  return v.f;
}

// ---------------- GEMM: C[M,N] = A[M,K] @ W[K,N] + bias[N] (fp32) ----------
__global__ __launch_bounds__(256) void gemm_bias_kernel(
    const float* __restrict__ A, const float* __restrict__ W,
    const float* __restrict__ bias, float* __restrict__ C,
    int M, int N, int K) {
  __shared__ float As[16][68];
  __shared__ float Bs[16][68];
  const int tid = threadIdx.x;
  const int bm = blockIdx.y * 64;
  const int bn = blockIdx.x * 64;
  const int mb = (tid >> 4) << 2;
  const int nb = (tid & 15) << 2;
  float acc[4][4] = {};
  for (int k0 = 0; k0 < K; k0 += 16) {
#pragma unroll
    for (int i = 0; i < 4; ++i) {
      int idx = tid + i * 256;
      int kk = idx & 15, m = idx >> 4;
      As[kk][m] = A[(size_t)(bm + m) * K + k0 + kk];
    }
#pragma unroll
    for (int i = 0; i < 4; ++i) {
      int idx = tid + i * 256;
      int n = idx & 63, kk = idx >> 6;
      Bs[kk][n] = W[(size_t)(k0 + kk) * N + bn + n];
    }
    __syncthreads();
#pragma unroll
    for (int kk = 0; kk < 16; ++kk) {
      float4 a4 = *(const float4*)&As[kk][mb];
      float4 b4 = *(const float4*)&Bs[kk][nb];
      float av[4] = {a4.x, a4.y, a4.z, a4.w};
      float bv[4] = {b4.x, b4.y, b4.z, b4.w};
#pragma unroll
      for (int i = 0; i < 4; ++i)
#pragma unroll
        for (int j = 0; j < 4; ++j)
          acc[i][j] = fmaf(av[i], bv[j], acc[i][j]);
    }
    __syncthreads();
  }
#pragma unroll
  for (int i = 0; i < 4; ++i) {
    float4 r;
    r.x = acc[i][0] + bias[bn + nb + 0];
    r.y = acc[i][1] + bias[bn + nb + 1];
    r.z = acc[i][2] + bias[bn + nb + 2];
    r.w = acc[i][3] + bias[bn + nb + 3];
    *(float4*)&C[(size_t)(bm + mb + i) * N + bn + nb] = r;
  }
}

// --------- RoPE(half=512) + per-head rmsnorm, Q -> bf16 hi/lo --------------
__global__ __launch_bounds__(1024) void rope_norm_q_kernel(
    const float* __restrict__ q, unsigned short* __restrict__ qnh,
    unsigned short* __restrict__ qnl) {
  const int s = blockIdx.x, b = blockIdx.y;
  const int t = threadIdx.x;
  const float* row = q + ((size_t)b * SEQ + s) * HID;
  const int j = t & 511;
  double invf = pow(10000.0, -(double)j / 512.0);
  double ang = (double)s * invf;
  float c = (float)cos(ang), sn = (float)sin(ang);
  float x1 = row[j], x2 = row[j + 512];
  float val = (t < 512) ? (x1 * c - x2 * sn) : (x2 * c + x1 * sn);
  float ss = val * val;
#pragma unroll
  for (int off = 1; off < 64; off <<= 1) ss += __shfl_xor(ss, off);
  float rn = rsqrtf(ss * (1.0f / 64.0f) + 1.1920929e-07f);
  float v = val * rn;
  unsigned short hi = f2bf(v);
  unsigned short lo = f2bf(v - bf2f(hi));
  int h = t >> 6, d = t & 63;
  size_t o = (((size_t)b * NH + h) * SEQ + s) * DH + d;
  qnh[o] = hi;
  qnl[o] = lo;
}

// --------- RoPE(half=128) + rmsnorm K -> bf16 hi/lo; V -> bf16 transposed --
__global__ __launch_bounds__(256) void rope_norm_kv_kernel(
    const float* __restrict__ k, const float* __restrict__ v,
    unsigned short* __restrict__ knh, unsigned short* __restrict__ knl,
    unsigned short* __restrict__ vt) {
  const int s = blockIdx.x, b = blockIdx.y;
  const int t = threadIdx.x;
  const float* krow = k + ((size_t)b * SEQ + s) * KVDIM;
  const float* vrow = v + ((size_t)b * SEQ + s) * KVDIM;
  const int j = t & 127;
  double invf = pow(10000.0, -(double)j / 128.0);
  double ang = (double)s * invf;
  float c = (float)cos(ang), sn = (float)sin(ang);
  float x1 = krow[j], x2 = krow[j + 128];
  float val = (t < 128) ? (x1 * c - x2 * sn) : (x2 * c + x1 * sn);
  float ss = val * val;
#pragma unroll
  for (int off = 1; off < 64; off <<= 1) ss += __shfl_xor(ss, off);
  float rn = rsqrtf(ss * (1.0f / 64.0f) + 1.1920929e-07f);
  float kv = val * rn;
  unsigned short hi = f2bf(kv);
  unsigned short lo = f2bf(kv - bf2f(hi));
  int h = t >> 6, d = t & 63;
  size_t o = (((size_t)b * NKV + h) * SEQ + s) * DH + d;
  knh[o] = hi;
  knl[o] = lo;
  // V transposed: [b][kv][d][s], plain bf16 (scattered 2B writes, tiny kernel)
  vt[(((size_t)b * NKV + h) * DH + d) * SEQ + s] = f2bf(vrow[t]);
}

// ------------------------- MFMA attention ----------------------------------
// Block = 4 waves = the 4 q-heads of one kv group, shared 32 q-rows.
// Grid (SEQ/32, NKV, BATCH) = 512 blocks. Fixed softmax max = 8 (rmsnorm
// Cauchy-Schwarz bound, mask == 0). QK^T uses bf16 hi/lo split (3 chains)
// for fp32-grade scores; P/V plain bf16. 16x16x32 MFMA (verified layouts):
//   A[m=lane&15][k=(lane>>4)*8+j]   B[k=(lane>>4)*8+j][n=lane&15]
//   C/D: col=lane&15, row=(lane>>4)*4+reg
__global__ __launch_bounds__(256) void attn_mfma_kernel(
    const unsigned short* __restrict__ qnh, const unsigned short* __restrict__ qnl,
    const unsigned short* __restrict__ knh, const unsigned short* __restrict__ knl,
    const unsigned short* __restrict__ vtb, const float* __restrict__ mask,
    float* __restrict__ out) {
  __shared__ unsigned short Ksh[32][72];   // K hi, pitch 72 (16B-aligned rows)
  __shared__ unsigned short Ksl[32][72];   // K lo
  __shared__ unsigned short Vts[64][40];   // V^T [d][j], pitch 40
  __shared__ float Ms[32][36];             // mask tile, pitch 36
  __shared__ unsigned short Ps[4][32][40]; // per-wave P, pitch 40

  const int b = blockIdx.z, kvh = blockIdx.y;
  const int q0 = blockIdx.x * 32;
  const int tid = threadIdx.x;
  const int wave = tid >> 6, lane = tid & 63;
  const int quad = lane >> 4, l16 = lane & 15;
  const int h = kvh * 4 + wave;

  // Q fragments (2 m-tiles x 2 k-frags), hi and lo
  bf16x8 qh[2][2], ql[2][2];
  {
    const unsigned short* qb_h = qnh + (((size_t)b * NH + h) * SEQ) * DH;
    const unsigned short* qb_l = qnl + (((size_t)b * NH + h) * SEQ) * DH;
#pragma unroll
    for (int mt = 0; mt < 2; ++mt)
#pragma unroll
      for (int kf = 0; kf < 2; ++kf) {
        size_t o = (size_t)(q0 + mt * 16 + l16) * DH + kf * 32 + quad * 8;
        qh[mt][kf] = *(const bf16x8*)(qb_h + o);
        ql[mt][kf] = *(const bf16x8*)(qb_l + o);
      }
  }

  f32x4 O[2][4] = {};
  float l_acc[2][4] = {};

  const unsigned short* Kbh = knh + ((size_t)b * NKV + kvh) * SEQ * DH;
  const unsigned short* Kbl = knl + ((size_t)b * NKV + kvh) * SEQ * DH;
  const unsigned short* Vb  = vtb + ((size_t)b * NKV + kvh) * DH * SEQ;
  const float* mbase = mask + ((size_t)b * SEQ + q0) * SEQ;

  for (int j0 = 0; j0 < SEQ; j0 += 32) {
    __syncthreads();
    {  // stage K hi/lo [32][64], V^T [64][32], mask [32][32]
      int j = tid >> 3, c = tid & 7;
      *(uint4*)&Ksh[j][c * 8] = *(const uint4*)(Kbh + (size_t)(j0 + j) * DH + c * 8);
      *(uint4*)&Ksl[j][c * 8] = *(const uint4*)(Kbl + (size_t)(j0 + j) * DH + c * 8);
      int d = tid >> 2, c2 = tid & 3;
      *(uint4*)&Vts[d][c2 * 8] = *(const uint4*)(Vb + (size_t)d * SEQ + j0 + c2 * 8);
      *(float4*)&Ms[j][c * 4] = *(const float4*)(mbase + (size_t)j * SEQ + j0 + c * 4);
    }
    __syncthreads();

    // B-fragments of K (hi/lo): n-tile nt covers j-cols nt*16..+16
    bf16x8 kbh[2][2], kbl[2][2];
#pragma unroll
    for (int nt = 0; nt < 2; ++nt)
#pragma unroll
      for (int kf = 0; kf < 2; ++kf) {
        kbh[nt][kf] = *(const bf16x8*)&Ksh[nt * 16 + l16][kf * 32 + quad * 8];
        kbl[nt][kf] = *(const bf16x8*)&Ksl[nt * 16 + l16][kf * 32 + quad * 8];
      }

    // QK^T with hi/lo split: C = qh*kh + ql*kh + qh*kl
    f32x4 C[2][2] = {};
#pragma unroll
    for (int mt = 0; mt < 2; ++mt)
#pragma unroll
      for (int nt = 0; nt < 2; ++nt) {
#pragma unroll
        for (int kf = 0; kf < 2; ++kf) {
          C[mt][nt] = __builtin_amdgcn_mfma_f32_16x16x32_bf16(qh[mt][kf], kbh[nt][kf], C[mt][nt], 0, 0, 0);
          C[mt][nt] = __builtin_amdgcn_mfma_f32_16x16x32_bf16(ql[mt][kf], kbh[nt][kf], C[mt][nt], 0, 0, 0);
          C[mt][nt] = __builtin_amdgcn_mfma_f32_16x16x32_bf16(qh[mt][kf], kbl[nt][kf], C[mt][nt], 0, 0, 0);
        }
      }

    // p = exp(score - 8), accumulate l, write P (bf16) for LDS re-layout
#pragma unroll
    for (int mt = 0; mt < 2; ++mt)
#pragma unroll
      for (int nt = 0; nt < 2; ++nt)
#pragma unroll
        for (int r = 0; r < 4; ++r) {
          int row = mt * 16 + quad * 4 + r;
          float p = __expf(fmaf(C[mt][nt][r], 0.125f, Ms[row][nt * 16 + l16] - 8.0f));
          l_acc[mt][r] += p;
          Ps[wave][row][nt * 16 + l16] = f2bf(p);
        }

    // PV: A = P (re-read in A-layout), B = V^T tiles
    bf16x8 pa[2], vbf[4];
#pragma unroll
    for (int mt = 0; mt < 2; ++mt)
      pa[mt] = *(const bf16x8*)&Ps[wave][mt * 16 + l16][quad * 8];
#pragma unroll
    for (int nt = 0; nt < 4; ++nt)
      vbf[nt] = *(const bf16x8*)&Vts[nt * 16 + l16][quad * 8];
#pragma unroll
    for (int mt = 0; mt < 2; ++mt)
#pragma unroll
      for (int nt = 0; nt < 4; ++nt)
        O[mt][nt] = __builtin_amdgcn_mfma_f32_16x16x32_bf16(pa[mt], vbf[nt], O[mt][nt], 0, 0, 0);
  }

  // reduce l across the 16 column-lanes (rows are identical within a quad)
#pragma unroll
  for (int mt = 0; mt < 2; ++mt)
#pragma unroll
    for (int r = 0; r < 4; ++r) {
#pragma unroll
      for (int off = 1; off < 16; off <<= 1)
        l_acc[mt][r] += __shfl_xor(l_acc[mt][r], off);
    }

#pragma unroll
  for (int mt = 0; mt < 2; ++mt)
#pragma unroll
    for (int r = 0; r < 4; ++r) {
      float inv = 1.0f / l_acc[mt][r];
      int s = q0 + mt * 16 + quad * 4 + r;
#pragma unroll
      for (int nt = 0; nt < 4; ++nt)
        out[((size_t)b * SEQ + s) * HID + h * DH + nt * 16 + l16] = O[mt][nt][r] * inv;
    }
}

extern "C" void kernel_launch(void* const* d_in, const int* in_sizes, int n_in,
                              void* d_out, int out_size, void* d_ws, size_t ws_size,
                              hipStream_t stream) {
  const float* hs   = (const float*)d_in[0];
  const float* mask = (const float*)d_in[1];
  const float* Wq   = (const float*)d_in[2];
  const float* bq   = (const float*)d_in[3];
  const float* Wk   = (const float*)d_in[4];
  const float* bk   = (const float*)d_in[5];
  const float* Wv   = (const float*)d_in[6];
  const float* bv   = (const float*)d_in[7];
  const float* Wo   = (const float*)d_in[8];
  const float* bo   = (const float*)d_in[9];
  float* out = (float*)d_out;
  char* ws = (char*)d_ws;

  // Workspace layout (bytes), total 46.0 MB <= 48 MB
  float*          q_proj = (float*)(ws);                    // 16 MB
  float*          k_proj = (float*)(ws + 16777216);         //  4 MB
  float*          v_proj = (float*)(ws + 20971520);         //  4 MB
  unsigned short* qnh    = (unsigned short*)(ws + 25165824);//  8 MB
  unsigned short* qnl    = (unsigned short*)(ws + 33554432);//  8 MB
  unsigned short* knh    = (unsigned short*)(ws + 41943040);//  2 MB
  unsigned short* knl    = (unsigned short*)(ws + 44040192);//  2 MB
  unsigned short* vtb    = (unsigned short*)(ws + 46137344);//  2 MB
  float*          attn_o = q_proj;  // reuse (q_proj consumed before attn)

  const int M = BATCH * SEQ;  // 4096
  dim3 blk(256);
  gemm_bias_kernel<<<dim3(HID / 64, M / 64), blk, 0, stream>>>(hs, Wq, bq, q_proj, M, HID, HID);
  gemm_bias_kernel<<<dim3(KVDIM / 64, M / 64), blk, 0, stream>>>(hs, Wk, bk, k_proj, M, KVDIM, HID);
  gemm_bias_kernel<<<dim3(KVDIM / 64, M / 64), blk, 0, stream>>>(hs, Wv, bv, v_proj, M, KVDIM, HID);
  rope_norm_q_kernel<<<dim3(SEQ, BATCH), dim3(1024), 0, stream>>>(q_proj, qnh, qnl);
  rope_norm_kv_kernel<<<dim3(SEQ, BATCH), dim3(256), 0, stream>>>(k_proj, v_proj, knh, knl, vtb);
  attn_mfma_kernel<<<dim3(SEQ / 32, NKV, BATCH), blk, 0, stream>>>(qnh, qnl, knh, knl, vtb, mask, attn_o);
  gemm_bias_kernel<<<dim3(HID / 64, M / 64), blk, 0, stream>>>(attn_o, Wo, bo, out, M, HID, HID);
}

// Round 3
// 304.981 us; speedup vs baseline: 4.9123x; 2.0705x over previous
//
#include <hip/hip_runtime.h>
#include <cmath>

#define SEQ 2048
#define BATCH 2
#define HID 1024
#define NH 16
#define NKV 4
#define DH 64
#define KVDIM 256
#define K32C 32          // K=1024 -> 32 chunks of 32

typedef __attribute__((ext_vector_type(8))) short bf16x8;
typedef __attribute__((ext_vector_type(4))) float f32x4;

static __device__ __forceinline__ unsigned short f2bf(float x) {
  union { float f; unsigned u; } v; v.f = x;
  unsigned r = v.u + 0x7fffu + ((v.u >> 16) & 1u);  // RNE
  return (unsigned short)(r >> 16);
}
static __device__ __forceinline__ float bf2f(unsigned short h) {
  union { unsigned u; float f; } v; v.u = ((unsigned)h) << 16;
  return v.f;
}
static __device__ __forceinline__ void gl_lds16(const unsigned short* g, unsigned short* l) {
  __builtin_amdgcn_global_load_lds(
      (const __attribute__((address_space(1))) unsigned int*)g,
      (__attribute__((address_space(3))) unsigned int*)l, 16, 0, 0);
}

// ---- pack A (fp32 [M][K=1024] row-major -> MFMA-A-frag-major bf16 hi[,lo]) ----
// slot = (m16b*32 + k32b)*64 + lane; lane=(quad,l16): m=l16, k=k32b*32+quad*8+j
template<bool HILO>
__global__ __launch_bounds__(256) void pack_a_kernel(
    const float* __restrict__ A, unsigned short* __restrict__ hi,
    unsigned short* __restrict__ lo) {
  int gid = blockIdx.x * 256 + threadIdx.x;
  int lane = gid & 63;
  int k32 = (gid >> 6) & 31;
  int m16 = gid >> 11;
  int quad = lane >> 4, l16 = lane & 15;
  const float* src = A + (size_t)(m16 * 16 + l16) * 1024 + k32 * 32 + quad * 8;
  float4 a0 = *(const float4*)src;
  float4 a1 = *(const float4*)(src + 4);
  float v[8] = {a0.x, a0.y, a0.z, a0.w, a1.x, a1.y, a1.z, a1.w};
  unsigned short h[8], l[8];
#pragma unroll
  for (int j = 0; j < 8; ++j) {
    h[j] = f2bf(v[j]);
    if (HILO) l[j] = f2bf(v[j] - bf2f(h[j]));
  }
  *(bf16x8*)(hi + (size_t)gid * 8) = *(bf16x8*)h;
  if (HILO) *(bf16x8*)(lo + (size_t)gid * 8) = *(bf16x8*)l;
}

// ---- pack B (fp32 W [K=1024][Nsrc] -> MFMA-B-frag-major bf16 hi[,lo]) ----
// slot = (n16b*32 + k32b)*64 + quad*16 + l16: n=n16b*16+l16, k=k32b*32+quad*8+j
template<bool HILO>
__global__ __launch_bounds__(256) void pack_b_kernel(
    const float* __restrict__ W, unsigned short* __restrict__ hi,
    unsigned short* __restrict__ lo, int Nsrc) {
  int gid = blockIdx.x * 256 + threadIdx.x;
  int lane = gid & 63;
  int k32 = (gid >> 6) & 31;
  int n16 = gid >> 11;
  int quad = lane >> 4, l16 = lane & 15;
  int n = n16 * 16 + l16, k = k32 * 32 + quad * 8;
  unsigned short h[8], l[8];
#pragma unroll
  for (int j = 0; j < 8; ++j) {
    float v = W[(size_t)(k + j) * Nsrc + n];
    h[j] = f2bf(v);
    if (HILO) l[j] = f2bf(v - bf2f(h[j]));
  }
  *(bf16x8*)(hi + (size_t)gid * 8) = *(bf16x8*)h;
  if (HILO) *(bf16x8*)(lo + (size_t)gid * 8) = *(bf16x8*)l;
}

__global__ __launch_bounds__(256) void bias_cat_kernel(
    const float* __restrict__ bq, const float* __restrict__ bk,
    const float* __restrict__ bv, float* __restrict__ dst) {
  int n = blockIdx.x * 256 + threadIdx.x;
  if (n < 1536)
    dst[n] = (n < 1024) ? bq[n] : (n < 1280 ? bk[n - 1024] : bv[n - 1280]);
}

// ---- packed-input MFMA GEMM: C[M][N] = A[M][1024] @ B[1024][N] + bias ----
// TM=64, TN=128, BK=32, 256 threads (4 waves, 2x2). CHAINS=1: plain bf16;
// CHAINS=3: hi*hi + lo*hi + hi*lo (fp32-grade). grid = (N/128, M/64).
template<int CHAINS, bool OUTBF16>
__global__ __launch_bounds__(256) void gemm_pk_kernel(
    const unsigned short* __restrict__ Ah, const unsigned short* __restrict__ Al,
    const unsigned short* __restrict__ Bh, const unsigned short* __restrict__ Bl,
    const float* __restrict__ bias, void* __restrict__ Cout, int N) {
  constexpr int NCH = (CHAINS == 3) ? 2 : 1;
  __shared__ unsigned short Asm[NCH][4 * 512];   // 4 m16-chunks x 64 lanes x 8
  __shared__ unsigned short Bsm[NCH][8 * 512];   // 8 n16-chunks
  const int tid = threadIdx.x;
  const int wave = tid >> 6, lane = tid & 63;
  const int wr = wave >> 1, wc = wave & 1;
  const int quad = lane >> 4, l16 = lane & 15;
  const size_t abase = ((size_t)(blockIdx.y * 4 + wave) * K32C) * 64 + lane;
  const size_t bbase0 = ((size_t)(blockIdx.x * 8 + wave) * K32C) * 64 + lane;
  const size_t bbase1 = ((size_t)(blockIdx.x * 8 + wave + 4) * K32C) * 64 + lane;
  f32x4 acc[2][4] = {};
  for (int k32 = 0; k32 < K32C; ++k32) {
    __syncthreads();
    gl_lds16(Ah + (abase + (size_t)k32 * 64) * 8, &Asm[0][wave * 512]);
    gl_lds16(Bh + (bbase0 + (size_t)k32 * 64) * 8, &Bsm[0][wave * 512]);
    gl_lds16(Bh + (bbase1 + (size_t)k32 * 64) * 8, &Bsm[0][(wave + 4) * 512]);
    if (CHAINS == 3) {
      gl_lds16(Al + (abase + (size_t)k32 * 64) * 8, &Asm[1][wave * 512]);
      gl_lds16(Bl + (bbase0 + (size_t)k32 * 64) * 8, &Bsm[1][wave * 512]);
      gl_lds16(Bl + (bbase1 + (size_t)k32 * 64) * 8, &Bsm[1][(wave + 4) * 512]);
    }
    __syncthreads();
    bf16x8 af[2][NCH], bfr[4][NCH];
#pragma unroll
    for (int mt = 0; mt < 2; ++mt)
#pragma unroll
      for (int ch = 0; ch < NCH; ++ch)
        af[mt][ch] = *(const bf16x8*)&Asm[ch][((wr * 2 + mt) * 64 + lane) * 8];
#pragma unroll
    for (int nt = 0; nt < 4; ++nt)
#pragma unroll
      for (int ch = 0; ch < NCH; ++ch)
        bfr[nt][ch] = *(const bf16x8*)&Bsm[ch][((wc * 4 + nt) * 64 + lane) * 8];
#pragma unroll
    for (int mt = 0; mt < 2; ++mt)
#pragma unroll
      for (int nt = 0; nt < 4; ++nt) {
        acc[mt][nt] = __builtin_amdgcn_mfma_f32_16x16x32_bf16(af[mt][0], bfr[nt][0], acc[mt][nt], 0, 0, 0);
        if (CHAINS == 3) {
          acc[mt][nt] = __builtin_amdgcn_mfma_f32_16x16x32_bf16(af[mt][1], bfr[nt][0], acc[mt][nt], 0, 0, 0);
          acc[mt][nt] = __builtin_amdgcn_mfma_f32_16x16x32_bf16(af[mt][0], bfr[nt][1], acc[mt][nt], 0, 0, 0);
        }
      }
  }
  const int n0 = blockIdx.x * 128 + wc * 64;
  const int m0 = blockIdx.y * 64 + wr * 32;
#pragma unroll
  for (int mt = 0; mt < 2; ++mt)
#pragma unroll
    for (int nt = 0; nt < 4; ++nt)
#pragma unroll
      for (int r = 0; r < 4; ++r) {
        int gm = m0 + mt * 16 + quad * 4 + r;
        int n = n0 + nt * 16 + l16;
        float v = acc[mt][nt][r] + bias[n];
        if (OUTBF16)
          ((unsigned short*)Cout)[(size_t)gm * N + n] = f2bf(v);
        else
          ((float*)Cout)[(size_t)gm * N + n] = v;
      }
}

// ---- RoPE(half=512) + per-head rmsnorm, Q (bf16 in) -> bf16 hi/lo ----------
__global__ __launch_bounds__(1024) void rope_norm_q_kernel(
    const unsigned short* __restrict__ qkv, unsigned short* __restrict__ qnh,
    unsigned short* __restrict__ qnl) {
  const int s = blockIdx.x, b = blockIdx.y;
  const int t = threadIdx.x;
  const unsigned short* row = qkv + ((size_t)b * SEQ + s) * 1536;
  const int j = t & 511;
  float invf = exp2f((float)j * (-13.287712379549449f / 512.0f));
  float ang = (float)s * invf;
  float c = cosf(ang), sn = sinf(ang);
  float x1 = bf2f(row[j]), x2 = bf2f(row[j + 512]);
  float val = (t < 512) ? (x1 * c - x2 * sn) : (x2 * c + x1 * sn);
  float ss = val * val;
#pragma unroll
  for (int off = 1; off < 64; off <<= 1) ss += __shfl_xor(ss, off);
  float rn = rsqrtf(ss * (1.0f / 64.0f) + 1.1920929e-07f);
  float v = val * rn;
  unsigned short hi = f2bf(v);
  unsigned short lo = f2bf(v - bf2f(hi));
  int h = t >> 6, d = t & 63;
  size_t o = (((size_t)b * NH + h) * SEQ + s) * DH + d;
  qnh[o] = hi;
  qnl[o] = lo;
}

// ---- RoPE(half=128)+rmsnorm K -> bf16 hi/lo; V -> bf16 transposed [d][s] ---
__global__ __launch_bounds__(256) void rope_norm_kv_kernel(
    const unsigned short* __restrict__ qkv, unsigned short* __restrict__ knh,
    unsigned short* __restrict__ knl, unsigned short* __restrict__ vt) {
  const int s = blockIdx.x, b = blockIdx.y;
  const int t = threadIdx.x;
  const unsigned short* row = qkv + ((size_t)b * SEQ + s) * 1536;
  const int j = t & 127;
  float invf = exp2f((float)j * (-13.287712379549449f / 128.0f));
  float ang = (float)s * invf;
  float c = cosf(ang), sn = sinf(ang);
  float x1 = bf2f(row[1024 + j]), x2 = bf2f(row[1024 + 128 + j]);
  float val = (t < 128) ? (x1 * c - x2 * sn) : (x2 * c + x1 * sn);
  float ss = val * val;
#pragma unroll
  for (int off = 1; off < 64; off <<= 1) ss += __shfl_xor(ss, off);
  float rn = rsqrtf(ss * (1.0f / 64.0f) + 1.1920929e-07f);
  float kv = val * rn;
  unsigned short hi = f2bf(kv);
  unsigned short lo = f2bf(kv - bf2f(hi));
  int h = t >> 6, d = t & 63;
  size_t o = (((size_t)b * NKV + h) * SEQ + s) * DH + d;
  knh[o] = hi;
  knl[o] = lo;
  vt[(((size_t)b * NKV + h) * DH + d) * SEQ + s] = row[1280 + t];
}

// ------------------------- MFMA attention (unchanged from round 2) ---------
__global__ __launch_bounds__(256) void attn_mfma_kernel(
    const unsigned short* __restrict__ qnh, const unsigned short* __restrict__ qnl,
    const unsigned short* __restrict__ knh, const unsigned short* __restrict__ knl,
    const unsigned short* __restrict__ vtb, const float* __restrict__ mask,
    float* __restrict__ out) {
  __shared__ unsigned short Ksh[32][72];
  __shared__ unsigned short Ksl[32][72];
  __shared__ unsigned short Vts[64][40];
  __shared__ float Ms[32][36];
  __shared__ unsigned short Ps[4][32][40];

  const int b = blockIdx.z, kvh = blockIdx.y;
  const int q0 = blockIdx.x * 32;
  const int tid = threadIdx.x;
  const int wave = tid >> 6, lane = tid & 63;
  const int quad = lane >> 4, l16 = lane & 15;
  const int h = kvh * 4 + wave;

  bf16x8 qh[2][2], ql[2][2];
  {
    const unsigned short* qb_h = qnh + (((size_t)b * NH + h) * SEQ) * DH;
    const unsigned short* qb_l = qnl + (((size_t)b * NH + h) * SEQ) * DH;
#pragma unroll
    for (int mt = 0; mt < 2; ++mt)
#pragma unroll
      for (int kf = 0; kf < 2; ++kf) {
        size_t o = (size_t)(q0 + mt * 16 + l16) * DH + kf * 32 + quad * 8;
        qh[mt][kf] = *(const bf16x8*)(qb_h + o);
        ql[mt][kf] = *(const bf16x8*)(qb_l + o);
      }
  }

  f32x4 O[2][4] = {};
  float l_acc[2][4] = {};

  const unsigned short* Kbh = knh + ((size_t)b * NKV + kvh) * SEQ * DH;
  const unsigned short* Kbl = knl + ((size_t)b * NKV + kvh) * SEQ * DH;
  const unsigned short* Vb  = vtb + ((size_t)b * NKV + kvh) * DH * SEQ;
  const float* mbase = mask + ((size_t)b * SEQ + q0) * SEQ;

  for (int j0 = 0; j0 < SEQ; j0 += 32) {
    __syncthreads();
    {
      int j = tid >> 3, c = tid & 7;
      *(uint4*)&Ksh[j][c * 8] = *(const uint4*)(Kbh + (size_t)(j0 + j) * DH + c * 8);
      *(uint4*)&Ksl[j][c * 8] = *(const uint4*)(Kbl + (size_t)(j0 + j) * DH + c * 8);
      int d = tid >> 2, c2 = tid & 3;
      *(uint4*)&Vts[d][c2 * 8] = *(const uint4*)(Vb + (size_t)d * SEQ + j0 + c2 * 8);
      *(float4*)&Ms[j][c * 4] = *(const float4*)(mbase + (size_t)j * SEQ + j0 + c * 4);
    }
    __syncthreads();

    bf16x8 kbh[2][2], kbl[2][2];
#pragma unroll
    for (int nt = 0; nt < 2; ++nt)
#pragma unroll
      for (int kf = 0; kf < 2; ++kf) {
        kbh[nt][kf] = *(const bf16x8*)&Ksh[nt * 16 + l16][kf * 32 + quad * 8];
        kbl[nt][kf] = *(const bf16x8*)&Ksl[nt * 16 + l16][kf * 32 + quad * 8];
      }

    f32x4 C[2][2] = {};
#pragma unroll
    for (int mt = 0; mt < 2; ++mt)
#pragma unroll
      for (int nt = 0; nt < 2; ++nt) {
#pragma unroll
        for (int kf = 0; kf < 2; ++kf) {
          C[mt][nt] = __builtin_amdgcn_mfma_f32_16x16x32_bf16(qh[mt][kf], kbh[nt][kf], C[mt][nt], 0, 0, 0);
          C[mt][nt] = __builtin_amdgcn_mfma_f32_16x16x32_bf16(ql[mt][kf], kbh[nt][kf], C[mt][nt], 0, 0, 0);
          C[mt][nt] = __builtin_amdgcn_mfma_f32_16x16x32_bf16(qh[mt][kf], kbl[nt][kf], C[mt][nt], 0, 0, 0);
        }
      }

#pragma unroll
    for (int mt = 0; mt < 2; ++mt)
#pragma unroll
      for (int nt = 0; nt < 2; ++nt)
#pragma unroll
        for (int r = 0; r < 4; ++r) {
          int row = mt * 16 + quad * 4 + r;
          float p = __expf(fmaf(C[mt][nt][r], 0.125f, Ms[row][nt * 16 + l16] - 8.0f));
          l_acc[mt][r] += p;
          Ps[wave][row][nt * 16 + l16] = f2bf(p);
        }

    bf16x8 pa[2], vbf[4];
#pragma unroll
    for (int mt = 0; mt < 2; ++mt)
      pa[mt] = *(const bf16x8*)&Ps[wave][mt * 16 + l16][quad * 8];
#pragma unroll
    for (int nt = 0; nt < 4; ++nt)
      vbf[nt] = *(const bf16x8*)&Vts[nt * 16 + l16][quad * 8];
#pragma unroll
    for (int mt = 0; mt < 2; ++mt)
#pragma unroll
      for (int nt = 0; nt < 4; ++nt)
        O[mt][nt] = __builtin_amdgcn_mfma_f32_16x16x32_bf16(pa[mt], vbf[nt], O[mt][nt], 0, 0, 0);
  }

#pragma unroll
  for (int mt = 0; mt < 2; ++mt)
#pragma unroll
    for (int r = 0; r < 4; ++r) {
#pragma unroll
      for (int off = 1; off < 16; off <<= 1)
        l_acc[mt][r] += __shfl_xor(l_acc[mt][r], off);
    }

#pragma unroll
  for (int mt = 0; mt < 2; ++mt)
#pragma unroll
    for (int r = 0; r < 4; ++r) {
      float inv = 1.0f / l_acc[mt][r];
      int s = q0 + mt * 16 + quad * 4 + r;
#pragma unroll
      for (int nt = 0; nt < 4; ++nt)
        out[((size_t)b * SEQ + s) * HID + h * DH + nt * 16 + l16] = O[mt][nt][r] * inv;
    }
}

extern "C" void kernel_launch(void* const* d_in, const int* in_sizes, int n_in,
                              void* d_out, int out_size, void* d_ws, size_t ws_size,
                              hipStream_t stream) {
  const float* hs   = (const float*)d_in[0];
  const float* mask = (const float*)d_in[1];
  const float* Wq   = (const float*)d_in[2];
  const float* bq   = (const float*)d_in[3];
  const float* Wk   = (const float*)d_in[4];
  const float* bk   = (const float*)d_in[5];
  const float* Wv   = (const float*)d_in[6];
  const float* bv   = (const float*)d_in[7];
  const float* Wo   = (const float*)d_in[8];
  const float* bo   = (const float*)d_in[9];
  float* out = (float*)d_out;
  char* ws = (char*)d_ws;
  const size_t MiB = 1048576;

  // Workspace (46 MiB total, time-multiplexed):
  unsigned short* hs_pk   = (unsigned short*)(ws);              // [0,8)   dead after QKV gemm
  unsigned short* qkvproj = (unsigned short*)(ws + 8 * MiB);    // [8,20)  dead after rope
  float*          attn_o  = (float*)(ws);                       // [0,16)  reuses the two above
  unsigned short* Wqkv_hi = (unsigned short*)(ws + 20 * MiB);   // [20,23)
  float*          bias_c  = (float*)(ws + 23 * MiB);            // 6 KB
  unsigned short* Wo_hi   = (unsigned short*)(ws + 20 * MiB);   // after QKV gemm
  unsigned short* Wo_lo   = (unsigned short*)(ws + 22 * MiB);
  unsigned short* qnh     = (unsigned short*)(ws + 24 * MiB);   // [24,32) dead after attn
  unsigned short* qnl     = (unsigned short*)(ws + 32 * MiB);   // [32,40) dead after attn
  unsigned short* ao_hi   = (unsigned short*)(ws + 24 * MiB);   // reuse qnh
  unsigned short* ao_lo   = (unsigned short*)(ws + 32 * MiB);   // reuse qnl
  unsigned short* knh     = (unsigned short*)(ws + 40 * MiB);
  unsigned short* knl     = (unsigned short*)(ws + 42 * MiB);
  unsigned short* vtb     = (unsigned short*)(ws + 44 * MiB);

  // --- pack inputs ---
  pack_a_kernel<false><<<2048, 256, 0, stream>>>(hs, hs_pk, nullptr);
  pack_b_kernel<false><<<512, 256, 0, stream>>>(Wq, Wqkv_hi, nullptr, 1024);
  pack_b_kernel<false><<<128, 256, 0, stream>>>(Wk, Wqkv_hi + (size_t)64 * 2048 * 8, nullptr, 256);
  pack_b_kernel<false><<<128, 256, 0, stream>>>(Wv, Wqkv_hi + (size_t)80 * 2048 * 8, nullptr, 256);
  bias_cat_kernel<<<6, 256, 0, stream>>>(bq, bk, bv, bias_c);

  // --- fused QKV projection (bf16 MFMA, N=1536) ---
  gemm_pk_kernel<1, true><<<dim3(12, 64), 256, 0, stream>>>(
      hs_pk, nullptr, Wqkv_hi, nullptr, bias_c, qkvproj, 1536);

  // Wo pack (W region free now)
  pack_b_kernel<true><<<512, 256, 0, stream>>>(Wo, Wo_hi, Wo_lo, 1024);

  // --- rope + rmsnorm (fp32 transcendentals) ---
  rope_norm_q_kernel<<<dim3(SEQ, BATCH), dim3(1024), 0, stream>>>(qkvproj, qnh, qnl);
  rope_norm_kv_kernel<<<dim3(SEQ, BATCH), dim3(256), 0, stream>>>(qkvproj, knh, knl, vtb);

  // --- attention (unchanged) ---
  attn_mfma_kernel<<<dim3(SEQ / 32, NKV, BATCH), 256, 0, stream>>>(
      qnh, qnl, knh, knl, vtb, mask, attn_o);

  // --- O projection: pack attn_o (hi/lo) then 3-chain MFMA GEMM ---
  pack_a_kernel<true><<<2048, 256, 0, stream>>>(attn_o, ao_hi, ao_lo);
  gemm_pk_kernel<3, false><<<dim3(8, 64), 256, 0, stream>>>(
      ao_hi, ao_lo, Wo_hi, Wo_lo, bo, out, 1024);
}

// Round 4
// 285.615 us; speedup vs baseline: 5.2453x; 1.0678x over previous
//
#include <hip/hip_runtime.h>
#include <cmath>

#define SEQ 2048
#define BATCH 2
#define HID 1024
#define NH 16
#define NKV 4
#define DH 64
#define KVDIM 256
#define K32C 32          // K=1024 -> 32 chunks of 32

typedef __attribute__((ext_vector_type(8))) short bf16x8;
typedef __attribute__((ext_vector_type(4))) float f32x4;

static __device__ __forceinline__ unsigned short f2bf(float x) {
  union { float f; unsigned u; } v; v.f = x;
  unsigned r = v.u + 0x7fffu + ((v.u >> 16) & 1u);  // RNE
  return (unsigned short)(r >> 16);
}
static __device__ __forceinline__ float bf2f(unsigned short h) {
  union { unsigned u; float f; } v; v.u = ((unsigned)h) << 16;
  return v.f;
}
static __device__ __forceinline__ void gl_lds16(const unsigned short* g, unsigned short* l) {
  __builtin_amdgcn_global_load_lds(
      (const __attribute__((address_space(1))) unsigned int*)g,
      (__attribute__((address_space(3))) unsigned int*)l, 16, 0, 0);
}

// ---- pack A (fp32 [M][K=1024] row-major -> MFMA-A-frag-major bf16 hi[,lo]) ----
template<bool HILO>
__global__ __launch_bounds__(256) void pack_a_kernel(
    const float* __restrict__ A, unsigned short* __restrict__ hi,
    unsigned short* __restrict__ lo) {
  int gid = blockIdx.x * 256 + threadIdx.x;
  int lane = gid & 63;
  int k32 = (gid >> 6) & 31;
  int m16 = gid >> 11;
  int quad = lane >> 4, l16 = lane & 15;
  const float* src = A + (size_t)(m16 * 16 + l16) * 1024 + k32 * 32 + quad * 8;
  float4 a0 = *(const float4*)src;
  float4 a1 = *(const float4*)(src + 4);
  float v[8] = {a0.x, a0.y, a0.z, a0.w, a1.x, a1.y, a1.z, a1.w};
  unsigned short h[8], l[8];
#pragma unroll
  for (int j = 0; j < 8; ++j) {
    h[j] = f2bf(v[j]);
    if (HILO) l[j] = f2bf(v[j] - bf2f(h[j]));
  }
  *(bf16x8*)(hi + (size_t)gid * 8) = *(bf16x8*)h;
  if (HILO) *(bf16x8*)(lo + (size_t)gid * 8) = *(bf16x8*)l;
}

// ---- pack A variant: normalize attention partials by l, then hi/lo split ----
__global__ __launch_bounds__(256) void pack_a_norm_kernel(
    const float* __restrict__ A, const float* __restrict__ lpart,
    unsigned short* __restrict__ hi, unsigned short* __restrict__ lo) {
  int gid = blockIdx.x * 256 + threadIdx.x;
  int lane = gid & 63;
  int k32 = (gid >> 6) & 31;
  int m16 = gid >> 11;
  int quad = lane >> 4, l16 = lane & 15;
  int m = m16 * 16 + l16;
  int b = m >> 11, s = m & 2047;
  int k0 = k32 * 32 + quad * 8;
  int h = k0 >> 6;
  float inv = 1.0f / lpart[(size_t)(b * NH + h) * SEQ + s];
  const float* src = A + (size_t)m * 1024 + k0;
  float4 a0 = *(const float4*)src;
  float4 a1 = *(const float4*)(src + 4);
  float v[8] = {a0.x, a0.y, a0.z, a0.w, a1.x, a1.y, a1.z, a1.w};
  unsigned short hh[8], ll[8];
#pragma unroll
  for (int j = 0; j < 8; ++j) {
    float x = v[j] * inv;
    hh[j] = f2bf(x);
    ll[j] = f2bf(x - bf2f(hh[j]));
  }
  *(bf16x8*)(hi + (size_t)gid * 8) = *(bf16x8*)hh;
  *(bf16x8*)(lo + (size_t)gid * 8) = *(bf16x8*)ll;
}

// ---- pack B (fp32 W [K=1024][Nsrc] -> MFMA-B-frag-major bf16 hi[,lo]) ----
template<bool HILO>
__global__ __launch_bounds__(256) void pack_b_kernel(
    const float* __restrict__ W, unsigned short* __restrict__ hi,
    unsigned short* __restrict__ lo, int Nsrc) {
  int gid = blockIdx.x * 256 + threadIdx.x;
  int lane = gid & 63;
  int k32 = (gid >> 6) & 31;
  int n16 = gid >> 11;
  int quad = lane >> 4, l16 = lane & 15;
  int n = n16 * 16 + l16, k = k32 * 32 + quad * 8;
  unsigned short h[8], l[8];
#pragma unroll
  for (int j = 0; j < 8; ++j) {
    float v = W[(size_t)(k + j) * Nsrc + n];
    h[j] = f2bf(v);
    if (HILO) l[j] = f2bf(v - bf2f(h[j]));
  }
  *(bf16x8*)(hi + (size_t)gid * 8) = *(bf16x8*)h;
  if (HILO) *(bf16x8*)(lo + (size_t)gid * 8) = *(bf16x8*)l;
}

__global__ __launch_bounds__(256) void bias_cat_kernel(
    const float* __restrict__ bq, const float* __restrict__ bk,
    const float* __restrict__ bv, float* __restrict__ dst) {
  int n = blockIdx.x * 256 + threadIdx.x;
  if (n < 1536)
    dst[n] = (n < 1024) ? bq[n] : (n < 1280 ? bk[n - 1024] : bv[n - 1280]);
}

// ---- packed-input MFMA GEMM (unchanged from round 3) ----
template<int CHAINS, bool OUTBF16>
__global__ __launch_bounds__(256) void gemm_pk_kernel(
    const unsigned short* __restrict__ Ah, const unsigned short* __restrict__ Al,
    const unsigned short* __restrict__ Bh, const unsigned short* __restrict__ Bl,
    const float* __restrict__ bias, void* __restrict__ Cout, int N) {
  constexpr int NCH = (CHAINS == 3) ? 2 : 1;
  __shared__ unsigned short Asm[NCH][4 * 512];
  __shared__ unsigned short Bsm[NCH][8 * 512];
  const int tid = threadIdx.x;
  const int wave = tid >> 6, lane = tid & 63;
  const int wr = wave >> 1, wc = wave & 1;
  const int quad = lane >> 4, l16 = lane & 15;
  const size_t abase = ((size_t)(blockIdx.y * 4 + wave) * K32C) * 64 + lane;
  const size_t bbase0 = ((size_t)(blockIdx.x * 8 + wave) * K32C) * 64 + lane;
  const size_t bbase1 = ((size_t)(blockIdx.x * 8 + wave + 4) * K32C) * 64 + lane;
  f32x4 acc[2][4] = {};
  for (int k32 = 0; k32 < K32C; ++k32) {
    __syncthreads();
    gl_lds16(Ah + (abase + (size_t)k32 * 64) * 8, &Asm[0][wave * 512]);
    gl_lds16(Bh + (bbase0 + (size_t)k32 * 64) * 8, &Bsm[0][wave * 512]);
    gl_lds16(Bh + (bbase1 + (size_t)k32 * 64) * 8, &Bsm[0][(wave + 4) * 512]);
    if (CHAINS == 3) {
      gl_lds16(Al + (abase + (size_t)k32 * 64) * 8, &Asm[1][wave * 512]);
      gl_lds16(Bl + (bbase0 + (size_t)k32 * 64) * 8, &Bsm[1][wave * 512]);
      gl_lds16(Bl + (bbase1 + (size_t)k32 * 64) * 8, &Bsm[1][(wave + 4) * 512]);
    }
    __syncthreads();
    bf16x8 af[2][NCH], bfr[4][NCH];
#pragma unroll
    for (int mt = 0; mt < 2; ++mt)
#pragma unroll
      for (int ch = 0; ch < NCH; ++ch)
        af[mt][ch] = *(const bf16x8*)&Asm[ch][((wr * 2 + mt) * 64 + lane) * 8];
#pragma unroll
    for (int nt = 0; nt < 4; ++nt)
#pragma unroll
      for (int ch = 0; ch < NCH; ++ch)
        bfr[nt][ch] = *(const bf16x8*)&Bsm[ch][((wc * 4 + nt) * 64 + lane) * 8];
#pragma unroll
    for (int mt = 0; mt < 2; ++mt)
#pragma unroll
      for (int nt = 0; nt < 4; ++nt) {
        acc[mt][nt] = __builtin_amdgcn_mfma_f32_16x16x32_bf16(af[mt][0], bfr[nt][0], acc[mt][nt], 0, 0, 0);
        if (CHAINS == 3) {
          acc[mt][nt] = __builtin_amdgcn_mfma_f32_16x16x32_bf16(af[mt][1], bfr[nt][0], acc[mt][nt], 0, 0, 0);
          acc[mt][nt] = __builtin_amdgcn_mfma_f32_16x16x32_bf16(af[mt][0], bfr[nt][1], acc[mt][nt], 0, 0, 0);
        }
      }
  }
  const int n0 = blockIdx.x * 128 + wc * 64;
  const int m0 = blockIdx.y * 64 + wr * 32;
#pragma unroll
  for (int mt = 0; mt < 2; ++mt)
#pragma unroll
    for (int nt = 0; nt < 4; ++nt)
#pragma unroll
      for (int r = 0; r < 4; ++r) {
        int gm = m0 + mt * 16 + quad * 4 + r;
        int n = n0 + nt * 16 + l16;
        float v = acc[mt][nt][r] + bias[n];
        if (OUTBF16)
          ((unsigned short*)Cout)[(size_t)gm * N + n] = f2bf(v);
        else
          ((float*)Cout)[(size_t)gm * N + n] = v;
      }
}

// ---- RoPE(half=512) + rmsnorm, Q -> A-frag-major packed bf16 hi/lo ---------
// Per (b,h): 128 m16-chunks x 2 kf x 512 shorts = 131072 shorts.
__global__ __launch_bounds__(1024) void rope_norm_q_kernel(
    const unsigned short* __restrict__ qkv, unsigned short* __restrict__ Qh,
    unsigned short* __restrict__ Ql) {
  const int s = blockIdx.x, b = blockIdx.y;
  const int t = threadIdx.x;
  const unsigned short* row = qkv + ((size_t)b * SEQ + s) * 1536;
  const int j = t & 511;
  float invf = exp2f((float)j * (-13.287712379549449f / 512.0f));
  float ang = (float)s * invf;
  float c = cosf(ang), sn = sinf(ang);
  float x1 = bf2f(row[j]), x2 = bf2f(row[j + 512]);
  float val = (t < 512) ? (x1 * c - x2 * sn) : (x2 * c + x1 * sn);
  float ss = val * val;
#pragma unroll
  for (int off = 1; off < 64; off <<= 1) ss += __shfl_xor(ss, off);
  float rn = rsqrtf(ss * (1.0f / 64.0f) + 1.1920929e-07f);
  float v = val * rn;
  unsigned short hi = f2bf(v);
  unsigned short lo = f2bf(v - bf2f(hi));
  int h = t >> 6, d = t & 63;
  // A-frag slot: m16=s>>4, l16=s&15, kf=d>>5, quad=(d>>3)&3, jj=d&7
  size_t o = (size_t)(b * NH + h) * 131072 +
             ((((size_t)(s >> 4) * 2 + (d >> 5)) * 64) + ((d >> 3) & 3) * 16 + (s & 15)) * 8 + (d & 7);
  Qh[o] = hi;
  Ql[o] = lo;
}

// ---- RoPE(half=128)+rmsnorm K -> B-frag-major hi; V -> B-frag-major --------
// Kpk per (b,kvh): 128 j16 x 2 kf x 512 = 131072 shorts.
// Vpk per (b,kvh): 4 d16 x 64 j32 x 512 = 131072 shorts.
__global__ __launch_bounds__(256) void rope_norm_kv_kernel(
    const unsigned short* __restrict__ qkv, unsigned short* __restrict__ Kpk,
    unsigned short* __restrict__ Vpk) {
  const int s = blockIdx.x, b = blockIdx.y;
  const int t = threadIdx.x;
  const unsigned short* row = qkv + ((size_t)b * SEQ + s) * 1536;
  const int j = t & 127;
  float invf = exp2f((float)j * (-13.287712379549449f / 128.0f));
  float ang = (float)s * invf;
  float c = cosf(ang), sn = sinf(ang);
  float x1 = bf2f(row[1024 + j]), x2 = bf2f(row[1024 + 128 + j]);
  float val = (t < 128) ? (x1 * c - x2 * sn) : (x2 * c + x1 * sn);
  float ss = val * val;
#pragma unroll
  for (int off = 1; off < 64; off <<= 1) ss += __shfl_xor(ss, off);
  float rn = rsqrtf(ss * (1.0f / 64.0f) + 1.1920929e-07f);
  float kv = val * rn;
  int h = t >> 6, d = t & 63;
  // K B-frag slot: j16=s>>4, l16=s&15, kf=d>>5, quad=(d>>3)&3, jj=d&7
  size_t ko = (size_t)(b * NKV + h) * 131072 +
              ((((size_t)(s >> 4) * 2 + (d >> 5)) * 64) + ((d >> 3) & 3) * 16 + (s & 15)) * 8 + (d & 7);
  Kpk[ko] = f2bf(kv);
  // V B-frag slot: d16=d>>4, l16=d&15, j32=s>>5, quad=(s>>3)&3, jj=s&7
  size_t vo = (size_t)(b * NKV + h) * 131072 +
              ((((size_t)(d >> 4) * 64 + (s >> 5)) * 64) + ((s >> 3) & 3) * 16 + (d & 15)) * 8 + (s & 7);
  Vpk[vo] = row[1280 + t];
}

// ------------------------- MFMA attention v2 -------------------------------
// grid (SEQ/32, NKV*2, BATCH) = 1024 blocks; block = 4 waves = 4 q-heads of
// one kv group; j-range split 2-way (blockIdx.y&1), partials accumulated via
// fp32 atomicAdd into attn_po (unnormalized) and l_part. Fixed softmax max=8.
// QK = 2 chains (qh*kh + ql*kh). l computed by MFMA against ones-B.
// All K/V staging frag-major via global_load_lds (conflict-free); P round
// trip via LDS pitch 72 shorts (write 2-way-free, read 16B-aligned b128).
__global__ __launch_bounds__(256, 4) void attn_mfma2_kernel(
    const unsigned short* __restrict__ Qh, const unsigned short* __restrict__ Ql,
    const unsigned short* __restrict__ Kpk, const unsigned short* __restrict__ Vpk,
    const float* __restrict__ mask, float* __restrict__ attn_po,
    float* __restrict__ l_part) {
  __shared__ unsigned short Kb[4 * 512];
  __shared__ unsigned short Vb[4 * 512];
  __shared__ float Msk[32][36];
  __shared__ unsigned short Ps[4][32 * 72];

  const int b = blockIdx.z;
  const int kvh = blockIdx.y >> 1, jh = blockIdx.y & 1;
  const int q0 = blockIdx.x * 32;
  const int tid = threadIdx.x, wave = tid >> 6, lane = tid & 63;
  const int quad = lane >> 4, l16 = lane & 15;
  const int h = kvh * 4 + wave;

  bf16x8 qh[2][2], ql[2][2];
  {
    const unsigned short* Qb_h = Qh + (size_t)(b * NH + h) * 131072;
    const unsigned short* Qb_l = Ql + (size_t)(b * NH + h) * 131072;
#pragma unroll
    for (int mt = 0; mt < 2; ++mt)
#pragma unroll
      for (int kf = 0; kf < 2; ++kf) {
        size_t o = ((((size_t)(q0 >> 4) + mt) * 2 + kf) * 64 + lane) * 8;
        qh[mt][kf] = *(const bf16x8*)(Qb_h + o);
        ql[mt][kf] = *(const bf16x8*)(Qb_l + o);
      }
  }

  const unsigned short* Kbase = Kpk + (size_t)(b * NKV + kvh) * 131072;
  const unsigned short* Vbase = Vpk + (size_t)(b * NKV + kvh) * 131072;

  bf16x8 ones;
#pragma unroll
  for (int i = 0; i < 8; ++i) ones[i] = (short)0x3F80;  // bf16 1.0

  f32x4 O[2][4] = {};
  f32x4 lAcc[2] = {};

  const int jbase = jh * (SEQ / 2);
  for (int jc = 0; jc < 32; ++jc) {
    const int j0 = jbase + jc * 32;
    __syncthreads();
    {
      // wave w stages K-chunk (nt=w>>1, kf=w&1) and V-chunk d16=w
      gl_lds16(Kbase + ((((size_t)(j0 >> 4) + (wave >> 1)) * 2 + (wave & 1)) * 64 + lane) * 8,
               &Kb[wave * 512]);
      gl_lds16(Vbase + (((size_t)wave * 64 + (j0 >> 5)) * 64 + lane) * 8,
               &Vb[wave * 512]);
      int mr = tid >> 3, c4 = tid & 7;
      float4 m4 = *(const float4*)(mask + ((size_t)b * SEQ + q0 + mr) * SEQ + j0 + c4 * 4);
      Msk[mr][c4 * 4 + 0] = m4.x - 8.0f;
      Msk[mr][c4 * 4 + 1] = m4.y - 8.0f;
      Msk[mr][c4 * 4 + 2] = m4.z - 8.0f;
      Msk[mr][c4 * 4 + 3] = m4.w - 8.0f;
    }
    __syncthreads();

    bf16x8 kbf[2][2], vbf[4];
#pragma unroll
    for (int nt = 0; nt < 2; ++nt)
#pragma unroll
      for (int kf = 0; kf < 2; ++kf)
        kbf[nt][kf] = *(const bf16x8*)&Kb[((nt * 2 + kf) * 64 + lane) * 8];
#pragma unroll
    for (int d16 = 0; d16 < 4; ++d16)
      vbf[d16] = *(const bf16x8*)&Vb[(d16 * 64 + lane) * 8];

#pragma unroll
    for (int mt = 0; mt < 2; ++mt)
#pragma unroll
      for (int nt = 0; nt < 2; ++nt) {
        f32x4 C = {};
        C = __builtin_amdgcn_mfma_f32_16x16x32_bf16(qh[mt][0], kbf[nt][0], C, 0, 0, 0);
        C = __builtin_amdgcn_mfma_f32_16x16x32_bf16(qh[mt][1], kbf[nt][1], C, 0, 0, 0);
        C = __builtin_amdgcn_mfma_f32_16x16x32_bf16(ql[mt][0], kbf[nt][0], C, 0, 0, 0);
        C = __builtin_amdgcn_mfma_f32_16x16x32_bf16(ql[mt][1], kbf[nt][1], C, 0, 0, 0);
#pragma unroll
        for (int r = 0; r < 4; ++r) {
          int row = mt * 16 + quad * 4 + r;
          float p = __expf(fmaf(C[r], 0.125f, Msk[row][nt * 16 + l16]));
          union { float f; unsigned u; } pu; pu.f = p;
          Ps[wave][row * 72 + nt * 16 + l16] = (unsigned short)((pu.u + 0x8000u) >> 16);
        }
      }

    bf16x8 pa[2];
#pragma unroll
    for (int mt = 0; mt < 2; ++mt)
      pa[mt] = *(const bf16x8*)&Ps[wave][(mt * 16 + l16) * 72 + quad * 8];
#pragma unroll
    for (int mt = 0; mt < 2; ++mt) {
      lAcc[mt] = __builtin_amdgcn_mfma_f32_16x16x32_bf16(pa[mt], ones, lAcc[mt], 0, 0, 0);
#pragma unroll
      for (int nt = 0; nt < 4; ++nt)
        O[mt][nt] = __builtin_amdgcn_mfma_f32_16x16x32_bf16(pa[mt], vbf[nt], O[mt][nt], 0, 0, 0);
    }
  }

#pragma unroll
  for (int mt = 0; mt < 2; ++mt)
#pragma unroll
    for (int r = 0; r < 4; ++r) {
      int s = q0 + mt * 16 + quad * 4 + r;
#pragma unroll
      for (int nt = 0; nt < 4; ++nt)
        atomicAdd(attn_po + ((size_t)b * SEQ + s) * HID + h * DH + nt * 16 + l16,
                  O[mt][nt][r]);
      if (l16 == 0)
        atomicAdd(l_part + (size_t)(b * NH + h) * SEQ + s, lAcc[mt][r]);
    }
}

extern "C" void kernel_launch(void* const* d_in, const int* in_sizes, int n_in,
                              void* d_out, int out_size, void* d_ws, size_t ws_size,
                              hipStream_t stream) {
  const float* hs   = (const float*)d_in[0];
  const float* mask = (const float*)d_in[1];
  const float* Wq   = (const float*)d_in[2];
  const float* bq   = (const float*)d_in[3];
  const float* Wk   = (const float*)d_in[4];
  const float* bk   = (const float*)d_in[5];
  const float* Wv   = (const float*)d_in[6];
  const float* bv   = (const float*)d_in[7];
  const float* Wo   = (const float*)d_in[8];
  const float* bo   = (const float*)d_in[9];
  float* out = (float*)d_out;
  char* ws = (char*)d_ws;
  const size_t MiB = 1048576;

  // Workspace (max concurrent ~44 MiB):
  unsigned short* hs_pk   = (unsigned short*)(ws);              // [0,8) dead after QKV gemm
  unsigned short* qkvproj = (unsigned short*)(ws + 8 * MiB);    // [8,20) dead after rope
  float*          attn_po = (float*)(ws);                       // [0,16) after rope
  float*          l_part  = (float*)(ws + 16 * MiB);            // [16,16.25)
  unsigned short* Wqkv_hi = (unsigned short*)(ws + 20 * MiB);   // [20,23) dead after QKV gemm
  unsigned short* Wo_hi   = (unsigned short*)(ws + 20 * MiB);   // [20,22) after QKV gemm
  unsigned short* Wo_lo   = (unsigned short*)(ws + 22 * MiB);   // [22,24)
  unsigned short* Qpk_h   = (unsigned short*)(ws + 24 * MiB);   // [24,32) dead after attn
  unsigned short* Qpk_l   = (unsigned short*)(ws + 32 * MiB);   // [32,40) dead after attn
  unsigned short* ao_hi   = (unsigned short*)(ws + 24 * MiB);   // reuse
  unsigned short* ao_lo   = (unsigned short*)(ws + 32 * MiB);   // reuse
  unsigned short* Kpk     = (unsigned short*)(ws + 40 * MiB);   // [40,42)
  unsigned short* Vpk     = (unsigned short*)(ws + 42 * MiB);   // [42,44)
  float*          bias_c  = (float*)(ws + 44 * MiB);            // 6 KB

  // --- pack inputs ---
  pack_a_kernel<false><<<2048, 256, 0, stream>>>(hs, hs_pk, nullptr);
  pack_b_kernel<false><<<512, 256, 0, stream>>>(Wq, Wqkv_hi, nullptr, 1024);
  pack_b_kernel<false><<<128, 256, 0, stream>>>(Wk, Wqkv_hi + (size_t)64 * 2048 * 8, nullptr, 256);
  pack_b_kernel<false><<<128, 256, 0, stream>>>(Wv, Wqkv_hi + (size_t)80 * 2048 * 8, nullptr, 256);
  bias_cat_kernel<<<6, 256, 0, stream>>>(bq, bk, bv, bias_c);

  // --- fused QKV projection (bf16 MFMA, N=1536) ---
  gemm_pk_kernel<1, true><<<dim3(12, 64), 256, 0, stream>>>(
      hs_pk, nullptr, Wqkv_hi, nullptr, bias_c, qkvproj, 1536);

  pack_b_kernel<true><<<512, 256, 0, stream>>>(Wo, Wo_hi, Wo_lo, 1024);

  // --- rope + rmsnorm -> frag-major packed Q/K/V ---
  rope_norm_q_kernel<<<dim3(SEQ, BATCH), dim3(1024), 0, stream>>>(qkvproj, Qpk_h, Qpk_l);
  rope_norm_kv_kernel<<<dim3(SEQ, BATCH), dim3(256), 0, stream>>>(qkvproj, Kpk, Vpk);

  // --- zero partial accumulators, then attention ---
  hipMemsetAsync(ws, 0, 16 * MiB + 262144, stream);
  attn_mfma2_kernel<<<dim3(SEQ / 32, NKV * 2, BATCH), 256, 0, stream>>>(
      Qpk_h, Qpk_l, Kpk, Vpk, mask, attn_po, l_part);

  // --- O projection: normalize+pack, then 3-chain MFMA GEMM ---
  pack_a_norm_kernel<<<2048, 256, 0, stream>>>(attn_po, l_part, ao_hi, ao_lo);
  gemm_pk_kernel<3, false><<<dim3(8, 64), 256, 0, stream>>>(
      ao_hi, ao_lo, Wo_hi, Wo_lo, bo, out, 1024);
}